// Round 6
// baseline (356.334 us; speedup 1.0000x reference)
//
#include <hip/hip_runtime.h>

#define H 128
#define RREL 8
#define NJ 9        // 8 relations + root
#define MT 32       // dsts per layer-block
#define LROW 1160   // agg LDS row stride in elems (1152 + 8 pad; 2320B = 145*16B)

typedef short bf16x8 __attribute__((ext_vector_type(8)));
typedef float f32x4 __attribute__((ext_vector_type(4)));
typedef unsigned short u16x8 __attribute__((ext_vector_type(8)));

static __device__ __forceinline__ unsigned short f2bf(float f) {
    unsigned int u = __float_as_uint(f);
    unsigned int r = (u + 0x7fffu + ((u >> 16) & 1u)) >> 16;
    return (unsigned short)r;
}
static __device__ __forceinline__ float bf2f(unsigned short u) {
    return __uint_as_float(((unsigned int)u) << 16);
}

__global__ void zero_kernel(int* p, long n) {
    long i = (long)blockIdx.x * blockDim.x + threadIdx.x;
    long stride = (long)gridDim.x * blockDim.x;
    for (; i < n; i += stride) p[i] = 0;
}

__global__ void count_kernel(const int* __restrict__ ei, const int* __restrict__ et,
                             int* __restrict__ cnt, int E) {
    int e = blockIdx.x * 256 + threadIdx.x;
    if (e >= E) return;
    int d = ei[E + e];
    int r = et[e];
    atomicAdd(&cnt[(size_t)d * RREL + r], 1);
}

__global__ void scan_block_kernel(const int* __restrict__ cnt, int* __restrict__ rploc,
                                  int* __restrict__ bsum, int N) {
    __shared__ int s[256];
    int t = threadIdx.x;
    int d = blockIdx.x * 256 + t;
    int v = 0;
    if (d < N) {
#pragma unroll
        for (int r = 0; r < RREL; ++r) v += cnt[(size_t)d * RREL + r];
    }
    s[t] = v;
    __syncthreads();
#pragma unroll
    for (int off = 1; off < 256; off <<= 1) {
        int u = 0;
        if (t >= off) u = s[t - off];
        __syncthreads();
        s[t] += u;
        __syncthreads();
    }
    if (d < N) rploc[d] = s[t] - v;
    if (t == 255) bsum[blockIdx.x] = s[255];
}

// finalize with inlined top-level scan of bsum (nb <= 256).
// rowptr[d] = dst-bin start; rowptr2[d*8+r] = (dst,rel)-subbin start; inv = 1/max(cnt,1)
__global__ void finalize_kernel(const int* __restrict__ cnt, const int* __restrict__ rploc,
                                const int* __restrict__ bsum, int* __restrict__ rowptr,
                                int* __restrict__ rowptr2, float* __restrict__ inv,
                                int N, int nb) {
    __shared__ int s[256];
    int t = threadIdx.x;
    int v = (t < nb) ? bsum[t] : 0;
    s[t] = v;
    __syncthreads();
#pragma unroll
    for (int off = 1; off < 256; off <<= 1) {
        int u = 0;
        if (t >= off) u = s[t - off];
        __syncthreads();
        s[t] += u;
        __syncthreads();
    }
    int boffB = (blockIdx.x == 0) ? 0 : s[blockIdx.x - 1];
    int d = blockIdx.x * 256 + t;
    if (d >= N) return;
    int rp = rploc[d] + boffB;
    rowptr[d] = rp;
    int run = rp;
#pragma unroll
    for (int r = 0; r < RREL; ++r) {
        int c = cnt[(size_t)d * RREL + r];
        rowptr2[(size_t)d * RREL + r] = run;
        inv[(size_t)d * RREL + r] = 1.0f / (float)max(c, 1);
        run += c;
    }
    if (d == N - 1) rowptr[N] = run;
}

// packed[pos] = src | (rel<<20), binned by (dst, rel) -> rel-sorted within each dst bin
__global__ void fill_kernel(const int* __restrict__ ei, const int* __restrict__ et,
                            int* __restrict__ cursor, const int* __restrict__ rowptr2,
                            int* __restrict__ packed, int E) {
    int e = blockIdx.x * 256 + threadIdx.x;
    if (e >= E) return;
    int d = ei[E + e];
    int r = et[e];
    size_t bin = (size_t)d * RREL + r;
    int pos = rowptr2[bin] + atomicAdd(&cursor[bin], 1);
    packed[pos] = ei[e] | (r << 20);
}

// Fused weight prep + x->bf16 conversion (grid-stride over both ranges).
// WTa[j][f][k] = W[j][k][f] (j<8) or root[k][f] (j==8); bias natural order.
__global__ void wcat_tobf_kernel(const float* __restrict__ W1, const float* __restrict__ r1,
                                 const float* __restrict__ W2, const float* __restrict__ r2,
                                 const float* __restrict__ b1, const float* __restrict__ b2,
                                 unsigned short* __restrict__ WTa1, unsigned short* __restrict__ WTa2,
                                 float* __restrict__ biasP,
                                 const float* __restrict__ x, unsigned short* __restrict__ xb,
                                 long nx) {
    const long per = (long)NJ * H * H;
    const long total = per + 2 * H + nx;
    for (long id = (long)blockIdx.x * 256 + threadIdx.x; id < total; id += (long)gridDim.x * 256) {
        if (id < per) {
            int j = (int)(id / (H * H));
            int fk = (int)(id - (long)j * (H * H));
            int f = fk >> 7, k = fk & 127;
            float v1 = (j < RREL) ? W1[((size_t)j * H + k) * H + f] : r1[(size_t)k * H + f];
            WTa1[id] = f2bf(v1);
            float v2 = (j < RREL) ? W2[((size_t)j * H + k) * H + f] : r2[(size_t)k * H + f];
            WTa2[id] = f2bf(v2);
        } else if (id < per + 2 * H) {
            int c = (int)(id - per);
            biasP[c] = (c < H) ? b1[c] : b2[c - H];
        } else {
            long i = id - per - 2 * H;
            xb[i] = f2bf(x[i]);
        }
    }
}

// flush the current (d,r) fp32 accumulator to its bf16 LDS slot
#define FLUSH()                                                                \
    do {                                                                       \
        if (rcur >= 0) {                                                       \
            float iv_ = __shfl(ivv, rcur);                                     \
            unsigned pw_ = ((unsigned)f2bf(a1 * iv_) << 16) |                  \
                           (unsigned)f2bf(a0 * iv_);                           \
            *(unsigned*)&rowp[rcur * H + c2] = pw_;                            \
        }                                                                      \
    } while (0)

// prologue load for pipeline slot S (edge S of the chunk, clamped)
#define PLD(S)                                                                 \
    do {                                                                       \
        int ec_ = (S) < cnt ? (S) : cnt - 1;                                   \
        sv##S = __builtin_amdgcn_readlane(pkv, ec_);                           \
        x##S = *(const unsigned*)&xin[(size_t)(sv##S & 0xFFFFF) * H + c2];     \
    } while (0)

// one pipelined edge step: decode (scalar) -> boundary flush (scalar branch)
// -> accumulate 2 features -> refill slot with edge e+8's load
#define RSTEP(S)                                                               \
    do {                                                                       \
        int e_ = e0 + (S);                                                     \
        int r_ = (int)((sv##S >> 20) & 7);                                     \
        if (r_ != rcur) { FLUSH(); rcur = r_; a0 = 0.f; a1 = 0.f; }            \
        if (e_ < cnt) {                                                        \
            a0 += __uint_as_float(x##S << 16);                                 \
            a1 += __uint_as_float(x##S & 0xFFFF0000u);                         \
        }                                                                      \
        int en_ = e_ + 8;                                                      \
        int ec_ = en_ < cnt ? en_ : cnt - 1;                                   \
        sv##S = __builtin_amdgcn_readlane(pkv, ec_);                           \
        x##S = *(const unsigned*)&xin[(size_t)(sv##S & 0xFFFFF) * H + c2];     \
    } while (0)

// Fused RGCN layer: aggregate-then-transform.
// Phase 1 (whole-wave-per-dst, scalar-uniform): one wave owns one dst; each
//   lane owns 2 features. Per edge: v_readlane the packed word to SGPR (decode
//   is scalar -> rel-boundary branch is s_cbranch, ZERO divergence), one
//   coalesced 256B row load (4B/lane), 2 fp32 adds. Depth-8 software pipeline
//   (named sv/x regs). Flush once per (d,r) bin: *inv, f2bf, 4B LDS write.
// Phase 2: out[32x128] = agg[32x1152] @ Wcat[1152x128] via MFMA, W from L2.
// Epilogue: +bias, relu?, coalesced store via LDS fp32 staging.
__global__ __launch_bounds__(512) void layer_kernel(const unsigned short* __restrict__ xin,
                                                    const unsigned short* __restrict__ WTa,
                                                    const float* __restrict__ biasP,
                                                    const float* __restrict__ inv,
                                                    const int* __restrict__ rowptr,
                                                    const int* __restrict__ packed,
                                                    float* __restrict__ outf,
                                                    unsigned short* __restrict__ outb,
                                                    int N, int relu) {
    __shared__ __align__(16) unsigned short aggS[MT * LROW];
    const int t = threadIdx.x;
    const int l = t & 63;
    const int wu = __builtin_amdgcn_readfirstlane(t >> 6);  // uniform wave id 0..7
    const int Mbase = blockIdx.x * MT;

    // init: zero rel slots, root slot = x[d]. Row g16=t>>4 belongs to wave
    // t>>6 == (t>>4)/4, i.e. the SAME wave that fills it in phase 1 -> no
    // barrier needed between init and phase 1.
    {
        const int g16 = t >> 4, fl = t & 15, kc = fl * 8;
        const int d = Mbase + g16;
        unsigned short* rowp0 = &aggS[g16 * LROW];
        u16x8 z = {0, 0, 0, 0, 0, 0, 0, 0};
#pragma unroll
        for (int c = 0; c < 8; ++c) *(u16x8*)&rowp0[(c * 16 + fl) * 8] = z;
        if (d < N) {
            *(u16x8*)&rowp0[RREL * H + kc] = *(const u16x8*)&xin[(size_t)d * H + kc];
        } else {
            *(u16x8*)&rowp0[RREL * H + kc] = z;
        }
    }

    // -------- Phase 1: wave wu processes dsts Mbase+wu*4 .. +3 --------
    const int c2 = l * 2;   // this lane's feature pair
    for (int q = 0; q < 4; ++q) {
        const int dl = wu * 4 + q;
        const int d = Mbase + dl;
        if (d >= N) break;
        const int beg = rowptr[d];
        const int end = rowptr[d + 1];
        if (end <= beg) continue;
        const float ivv = inv[(size_t)d * RREL + (l & 7)];  // lanes hold the 8 inv vals
        unsigned short* rowp = &aggS[dl * LROW];
        float a0 = 0.f, a1 = 0.f;
        int rcur = -1;
        for (int base = beg; base < end; base += 64) {
            int cnt = end - base; if (cnt > 64) cnt = 64;
            int pidx = base + l; if (pidx > end - 1) pidx = end - 1;
            const int pkv = packed[pidx];   // 64 edges' packed words, one per lane
            unsigned sv0, sv1, sv2, sv3, sv4, sv5, sv6, sv7;
            unsigned x0, x1, x2, x3, x4, x5, x6, x7;
            PLD(0); PLD(1); PLD(2); PLD(3); PLD(4); PLD(5); PLD(6); PLD(7);
            for (int e0 = 0; e0 < cnt; e0 += 8) {
                RSTEP(0); RSTEP(1); RSTEP(2); RSTEP(3);
                RSTEP(4); RSTEP(5); RSTEP(6); RSTEP(7);
            }
        }
        FLUSH();
    }

    __syncthreads();

    // -------- Phase 2: wave wu owns output cols [wu*16, wu*16+16) --------
    const int colb = l & 15, quad = l >> 4;
    const int fcol = wu * 16 + colb;
    const f32x4 fz = {0.f, 0.f, 0.f, 0.f};
    f32x4 acc0 = fz, acc1 = fz;
    const unsigned short* arow0 = &aggS[colb * LROW];
    const unsigned short* arow1 = &aggS[(16 + colb) * LROW];
#pragma unroll
    for (int j = 0; j < NJ; ++j) {
#pragma unroll
        for (int ks = 0; ks < 4; ++ks) {
            const int kl = ks * 32 + quad * 8;
            bf16x8 b = *(const bf16x8*)&WTa[((size_t)j * H + fcol) * H + kl];
            bf16x8 a0f = *(const bf16x8*)&arow0[j * H + kl];
            bf16x8 a1f = *(const bf16x8*)&arow1[j * H + kl];
            acc0 = __builtin_amdgcn_mfma_f32_16x16x32_bf16(a0f, b, acc0, 0, 0, 0);
            acc1 = __builtin_amdgcn_mfma_f32_16x16x32_bf16(a1f, b, acc1, 0, 0, 0);
        }
    }

    __syncthreads();  // all aggS reads done; reuse as fp32 staging [32][132]
    float* stg = (float*)aggS;
    const float bcol = biasP[fcol];
#pragma unroll
    for (int i = 0; i < 4; ++i) {
        float v0 = acc0[i] + bcol;
        float v1 = acc1[i] + bcol;
        if (relu) { v0 = fmaxf(v0, 0.f); v1 = fmaxf(v1, 0.f); }
        stg[(quad * 4 + i) * 132 + fcol] = v0;
        stg[(16 + quad * 4 + i) * 132 + fcol] = v1;
    }
    __syncthreads();
    {
        int row = t >> 4;           // 0..31
        int fl = t & 15;
        int dd = Mbase + row;
        if (dd < N) {
            int c0 = fl * 8;
            f32x4 p0 = *(const f32x4*)&stg[row * 132 + c0];
            f32x4 p1 = *(const f32x4*)&stg[row * 132 + c0 + 4];
            if (outf) {
                *(f32x4*)&outf[(size_t)dd * H + c0] = p0;
                *(f32x4*)&outf[(size_t)dd * H + c0 + 4] = p1;
            } else {
                u16x8 o;
#pragma unroll
                for (int j = 0; j < 4; ++j) { o[j] = f2bf(p0[j]); o[4 + j] = f2bf(p1[j]); }
                *(u16x8*)&outb[(size_t)dd * H + c0] = o;
            }
        }
    }
}

extern "C" void kernel_launch(void* const* d_in, const int* in_sizes, int n_in,
                              void* d_out, int out_size, void* d_ws, size_t ws_size,
                              hipStream_t stream) {
    const int* edge_index = (const int*)d_in[0];
    const int* edge_type  = (const int*)d_in[1];
    const float* node_emb = (const float*)d_in[2];
    const float* W1    = (const float*)d_in[3];
    const float* root1 = (const float*)d_in[4];
    const float* b1    = (const float*)d_in[5];
    const float* W2    = (const float*)d_in[6];
    const float* root2 = (const float*)d_in[7];
    const float* b2    = (const float*)d_in[8];
    float* out = (float*)d_out;

    const int E = in_sizes[1];
    const int N = in_sizes[2] / H;

    char* base = (char*)d_ws;
    size_t off = 0;
    auto take = [&](size_t bytes) { size_t o = off; off = (off + bytes + 63) & ~(size_t)63; return o; };
    int*   cnt     = (int*)  (base + take((size_t)N * RREL * 4));
    int*   cursor8 = (int*)  (base + take((size_t)N * RREL * 4));  // adjacent to cnt: single zero pass
    int*   rploc   = (int*)  (base + take((size_t)N * 4));
    int*   bsum    = (int*)  (base + take(256 * 4));
    int*   rowptr  = (int*)  (base + take(((size_t)N + 1) * 4));
    int*   rowptr2 = (int*)  (base + take((size_t)N * RREL * 4));
    float* inv     = (float*)(base + take((size_t)N * RREL * 4));
    int*   packed  = (int*)  (base + take((size_t)E * 4));
    unsigned short* WTa1 = (unsigned short*)(base + take((size_t)NJ * H * H * 2));
    unsigned short* WTa2 = (unsigned short*)(base + take((size_t)NJ * H * H * 2));
    float* biasP   = (float*)(base + take(2 * H * 4));
    unsigned short* xb  = (unsigned short*)(base + take((size_t)N * H * 2));
    unsigned short* hb  = (unsigned short*)(base + take((size_t)N * H * 2));
    (void)ws_size;

    const int nbScan = (N + 255) / 256;

    zero_kernel<<<512, 256, 0, stream>>>(cnt, (long)N * (2 * RREL));  // cnt + cursor8
    count_kernel<<<(E + 255) / 256, 256, 0, stream>>>(edge_index, edge_type, cnt, E);
    scan_block_kernel<<<nbScan, 256, 0, stream>>>(cnt, rploc, bsum, N);
    finalize_kernel<<<nbScan, 256, 0, stream>>>(cnt, rploc, bsum, rowptr, rowptr2, inv, N, nbScan);
    fill_kernel<<<(E + 255) / 256, 256, 0, stream>>>(edge_index, edge_type, cursor8, rowptr2, packed, E);
    wcat_tobf_kernel<<<2048, 256, 0, stream>>>(W1, root1, W2, root2, b1, b2,
                                               WTa1, WTa2, biasP, node_emb, xb, (long)N * H);

    const int gl = (N + MT - 1) / MT;
    layer_kernel<<<gl, 512, 0, stream>>>(xb, WTa1, biasP, inv, rowptr, packed,
                                         nullptr, hb, N, 1);
    layer_kernel<<<gl, 512, 0, stream>>>(hb, WTa2, biasP + H, inv, rowptr, packed,
                                         out, nullptr, N, 0);
}